// Round 2
// baseline (896.345 us; speedup 1.0000x reference)
//
#include <hip/hip_runtime.h>
#include <hip/hip_bf16.h>
#include <cstdint>

#define NNUM 100
#define NCAT 100
#define CATC 100
#define NCOND 128
#define GN_EPS 1e-5f

typedef __attribute__((ext_vector_type(8))) short bfrag8;   // 8 bf16 = 4 VGPRs
typedef __attribute__((ext_vector_type(4))) float accf4;    // 4 fp32 acc

__device__ __forceinline__ float sigmoidf_(float x) { return 1.0f / (1.0f + __expf(-x)); }

__device__ __forceinline__ ushort f2bf(float f) {
    uint32_t u = __builtin_bit_cast(uint32_t, f);
    u += 0x7fffu + ((u >> 16) & 1u);   // round-to-nearest-even
    return (ushort)(u >> 16);
}
__device__ __forceinline__ float bf2f(ushort h) {
    return __builtin_bit_cast(float, (uint32_t)h << 16);
}

// ---------------------------------------------------------------------------
// Pass 1: per-column (g) GEMM with split-bf16 (hi/lo) 3-term MFMA.
// Block = (b_tile=128 rows, one g), 256 threads. K chunked in halves of 64 so
// LDS (A hi/lo + W hi/lo frag planes) = 64 KB static -> 2 blocks/CU.
//   z = A_hi@W_hi + A_hi@W_lo + A_lo@W_hi   (error ~1e-5 pre-sigmoid)
// DIRECT=0: write ws[b][g][c] coalesced.  DIRECT=1: scatter to out (fallback).
// ---------------------------------------------------------------------------
template<int DIRECT>
__global__ __launch_bounds__(256, 2)
void cat_gemm_kernel(const int* __restrict__ x_cat,
                     const float* __restrict__ emb_table,
                     const float* __restrict__ gn_w,
                     const float* __restrict__ gn_b,
                     const float* __restrict__ W_cat,
                     const float* __restrict__ b_cat,
                     float* __restrict__ dst)
{
    const int g    = blockIdx.y;
    const int b0   = blockIdx.x * 128;
    const int tid  = threadIdx.x;
    const int lane = tid & 63;
    const int w    = tid >> 6;    // wave 0..3

    // frag-major chunked LDS: [plane][(tile*2+kk)*64*8 + lane*8 + j], 16 KB/plane
    __shared__ __align__(16) ushort Wc[2][8192];   // B operand hi/lo (32 KB)
    __shared__ __align__(16) ushort Ac[2][8192];   // A operand hi/lo (32 KB)

    // ---- stats pass: mean/rsig/idx for this wave's 32 rows -> lane-r registers ----
    float mw = 0.f, rw = 0.f;
    int   iw = 0;
    for (int r = 0; r < 32; ++r) {
        int m = w * 32 + r;
        int b = b0 + m;
        int idx = x_cat[b * NCAT + g];
        const float2* row = (const float2*)(emb_table + ((size_t)(g * CATC + idx) << 7));
        float2 v = row[lane];
        float s  = v.x + v.y;
        float ss = v.x * v.x + v.y * v.y;
        #pragma unroll
        for (int off = 32; off > 0; off >>= 1) {
            s  += __shfl_xor(s,  off, 64);
            ss += __shfl_xor(ss, off, 64);
        }
        float mean = s * (1.0f / 128.0f);
        float var  = ss * (1.0f / 128.0f) - mean * mean;
        float rsig = rsqrtf(var + GN_EPS);
        if (lane == r) { mw = mean; rw = rsig; iw = idx; }
    }

    accf4 acc[2][8];
    #pragma unroll
    for (int gi = 0; gi < 2; ++gi)
        #pragma unroll
        for (int t = 0; t < 8; ++t)
            acc[gi][t] = (accf4){0.f, 0.f, 0.f, 0.f};

    const float* Wg = W_cat + ((size_t)g << 14);

    for (int ch = 0; ch < 2; ++ch) {
        __syncthreads();   // protect LDS reuse across chunks

        // ---- stage W chunk: rows k = ch*64 .. ch*64+63, hi/lo split ----
        #pragma unroll 2
        for (int it = 0; it < 8; ++it) {
            int lin4 = it * 256 + tid;               // 0..2047 float4s in chunk
            int kl   = lin4 >> 5;                    // k_local 0..63
            int c4   = (lin4 & 31) << 2;
            float4 v = ((const float4*)Wg)[(ch << 11) + lin4];
            int kk = kl >> 5, j = kl & 7, lq = ((kl >> 3) & 3) << 4;
            float vv[4] = {v.x, v.y, v.z, v.w};
            #pragma unroll
            for (int e = 0; e < 4; ++e) {
                int c  = c4 + e;
                int t  = c >> 4;
                int lf = (c & 15) | lq;
                int o  = (((t * 2 + kk) * 64 + lf) << 3) + j;
                ushort h = f2bf(vv[e]);
                Wc[0][o] = h;
                Wc[1][o] = f2bf(vv[e] - bf2f(h));
            }
        }

        // ---- stage A chunk: this lane's channel = ch*64 + lane ----
        {
            int cg = ch * 64 + lane;                 // global feature index
            float gwv = gn_w[g * NCOND + cg];
            float gbv = gn_b[g * NCOND + cg];
            int kk = lane >> 5, j = lane & 7;
            int lq = ((lane >> 3) & 3) << 4;
            for (int r = 0; r < 32; ++r) {
                int m   = w * 32 + r;
                int idx = __shfl(iw, r, 64);
                float mu = __shfl(mw, r, 64);
                float rs = __shfl(rw, r, 64);
                float v = emb_table[(((size_t)(g * CATC + idx)) << 7) + cg];
                float n = (v - mu) * rs * gwv + gbv;
                int grp = m >> 4;
                int lf  = (m & 15) | lq;
                int o   = (((grp * 2 + kk) * 64 + lf) << 3) + j;
                ushort h = f2bf(n);
                Ac[0][o] = h;
                Ac[1][o] = f2bf(n - bf2f(h));
            }
        }
        __syncthreads();

        // ---- MFMA: wave w computes m-groups {w, w+4} x all 8 c-tiles ----
        #pragma unroll
        for (int kk = 0; kk < 2; ++kk) {
            bfrag8 ah0 = *(const bfrag8*)&Ac[0][((( w      * 2 + kk) * 64 + lane) << 3)];
            bfrag8 ah1 = *(const bfrag8*)&Ac[0][((((w + 4) * 2 + kk) * 64 + lane) << 3)];
            bfrag8 al0 = *(const bfrag8*)&Ac[1][((( w      * 2 + kk) * 64 + lane) << 3)];
            bfrag8 al1 = *(const bfrag8*)&Ac[1][((((w + 4) * 2 + kk) * 64 + lane) << 3)];
            #pragma unroll
            for (int t = 0; t < 8; ++t) {
                bfrag8 wh = *(const bfrag8*)&Wc[0][(((t * 2 + kk) * 64 + lane) << 3)];
                bfrag8 wl = *(const bfrag8*)&Wc[1][(((t * 2 + kk) * 64 + lane) << 3)];
                acc[0][t] = __builtin_amdgcn_mfma_f32_16x16x32_bf16(ah0, wh, acc[0][t], 0, 0, 0);
                acc[0][t] = __builtin_amdgcn_mfma_f32_16x16x32_bf16(ah0, wl, acc[0][t], 0, 0, 0);
                acc[0][t] = __builtin_amdgcn_mfma_f32_16x16x32_bf16(al0, wh, acc[0][t], 0, 0, 0);
                acc[1][t] = __builtin_amdgcn_mfma_f32_16x16x32_bf16(ah1, wh, acc[1][t], 0, 0, 0);
                acc[1][t] = __builtin_amdgcn_mfma_f32_16x16x32_bf16(ah1, wl, acc[1][t], 0, 0, 0);
                acc[1][t] = __builtin_amdgcn_mfma_f32_16x16x32_bf16(al1, wh, acc[1][t], 0, 0, 0);
            }
        }
    }

    // ---- epilogue: + b_cat, sigmoid, store ----
    const float* bcg = b_cat + g * NCOND;
    const int colL = lane & 15;
    const int quad = lane >> 4;
    #pragma unroll
    for (int t = 0; t < 8; ++t) {
        int c = t * 16 + colL;
        float bc = bcg[c];
        #pragma unroll
        for (int gi = 0; gi < 2; ++gi) {
            int mbase = (w + gi * 4) * 16 + quad * 4;
            #pragma unroll
            for (int r = 0; r < 4; ++r) {
                int b = b0 + mbase + r;
                float v = sigmoidf_(acc[gi][t][r] + bc);
                if (DIRECT) {
                    dst[(size_t)b * (128 * 200) + (size_t)c * 200 + 100 + g] = v;
                } else {
                    dst[(size_t)b * (NCAT * NCOND) + g * NCOND + c] = v;
                }
            }
        }
    }
}

// ---------------------------------------------------------------------------
// Transpose W_num/b_num (100x128 -> 128x100) into ws for coalesced pass-2 reads
// ---------------------------------------------------------------------------
__global__ __launch_bounds__(256)
void transpose_wn(const float* __restrict__ W_num, const float* __restrict__ b_num,
                  float* __restrict__ Wt, float* __restrict__ Bt)
{
    int idx = blockIdx.x * 256 + threadIdx.x;
    if (idx < NCOND * NNUM) {
        int c = idx / NNUM, j = idx - c * NNUM;
        Wt[idx] = W_num[j * NCOND + c];
        Bt[idx] = b_num[j * NCOND + c];
    }
}

// ---------------------------------------------------------------------------
// Pass 2: per-sample. LDS-transpose the (100x128) cat tile, fuse num branch,
// write fully-coalesced 200-float rows of out[b, :, :].
// ---------------------------------------------------------------------------
__global__ __launch_bounds__(256)
void finalize_kernel(const float* __restrict__ ws_cat,
                     const float* __restrict__ Wt,   // [c][j]
                     const float* __restrict__ Bt,   // [c][j]
                     const float* __restrict__ x_num,
                     float* __restrict__ out)
{
    const int b   = blockIdx.x;
    const int tid = threadIdx.x;
    __shared__ float T[NCAT * 129];   // pad 129 -> conflict-free strided reads
    __shared__ float xr[NNUM];

    if (tid < NNUM) xr[tid] = x_num[b * NNUM + tid];

    const float4* src = (const float4*)(ws_cat + (size_t)b * (NCAT * NCOND));
    #pragma unroll 4
    for (int it = 0; it < 13; ++it) {
        int i4 = it * 256 + tid;
        if (i4 < (NCAT * NCOND) / 4) {
            float4 v = src[i4];
            int base = i4 * 4;
            int gg = base >> 7;
            int cc = base & 127;
            float* d = &T[gg * 129 + cc];
            d[0] = v.x; d[1] = v.y; d[2] = v.z; d[3] = v.w;
        }
    }
    __syncthreads();

    float* outb = out + (size_t)b * (NCOND * 200);
    #pragma unroll 4
    for (int it = 0; it < 100; ++it) {
        int o = it * 256 + tid;          // 0..25599
        int c = o / 200;
        int j = o - c * 200;
        float v;
        if (j < NNUM) {
            v = sigmoidf_(xr[j] * Wt[c * NNUM + j] + Bt[c * NNUM + j]);
        } else {
            v = T[(j - NNUM) * 129 + c];
        }
        outb[o] = v;
    }
}

// ---------------------------------------------------------------------------
// Fallback num-branch kernel (only used if ws too small for two-pass)
// ---------------------------------------------------------------------------
__global__ __launch_bounds__(256)
void num_direct(const float* __restrict__ x_num, const float* __restrict__ W_num,
                const float* __restrict__ b_num, float* __restrict__ out, int B)
{
    size_t i = (size_t)blockIdx.x * 256 + threadIdx.x;
    size_t total = (size_t)B * NCOND * NNUM;
    if (i >= total) return;
    int n = (int)(i % NNUM);
    size_t t = i / NNUM;
    int c = (int)(t % NCOND);
    int b = (int)(t / NCOND);
    float v = sigmoidf_(x_num[b * NNUM + n] * W_num[n * NCOND + c] + b_num[n * NCOND + c]);
    out[(size_t)b * (NCOND * 200) + (size_t)c * 200 + n] = v;
}

extern "C" void kernel_launch(void* const* d_in, const int* in_sizes, int n_in,
                              void* d_out, int out_size, void* d_ws, size_t ws_size,
                              hipStream_t stream)
{
    const float* x_num  = (const float*)d_in[0];
    const int*   x_cat  = (const int*)  d_in[1];
    const float* W_num  = (const float*)d_in[2];
    const float* b_num  = (const float*)d_in[3];
    const float* emb    = (const float*)d_in[4];
    const float* gn_w   = (const float*)d_in[5];
    const float* gn_b   = (const float*)d_in[6];
    const float* W_cat  = (const float*)d_in[7];
    const float* b_cat  = (const float*)d_in[8];
    float* out = (float*)d_out;

    const int B = in_sizes[0] / NNUM;                 // 4096
    const size_t cat_bytes = (size_t)B * NCAT * NCOND * sizeof(float);
    const size_t need = cat_bytes + 2 * (size_t)NCOND * NNUM * sizeof(float);

    dim3 gemm_grid(B / 128, NCAT);

    if (ws_size >= need) {
        float* ws_cat = (float*)d_ws;
        float* Wt = (float*)((char*)d_ws + cat_bytes);
        float* Bt = Wt + NCOND * NNUM;
        transpose_wn<<<(NCOND * NNUM + 255) / 256, 256, 0, stream>>>(W_num, b_num, Wt, Bt);
        cat_gemm_kernel<0><<<gemm_grid, 256, 0, stream>>>(x_cat, emb, gn_w, gn_b, W_cat, b_cat, ws_cat);
        finalize_kernel<<<B, 256, 0, stream>>>(ws_cat, Wt, Bt, x_num, out);
    } else {
        // fallback: correct but strided writes
        cat_gemm_kernel<1><<<gemm_grid, 256, 0, stream>>>(x_cat, emb, gn_w, gn_b, W_cat, b_cat, out);
        size_t total = (size_t)B * NCOND * NNUM;
        num_direct<<<(total + 255) / 256, 256, 0, stream>>>(x_num, W_num, b_num, out, B);
    }
}